// Round 1
// baseline (344.751 us; speedup 1.0000x reference)
//
#include <hip/hip_runtime.h>
#include <hip/hip_bf16.h>

#define BB 8
#define CC 128
#define HH 96
#define WW 96
#define HWH (HH*WW)   // 9216
#define NH 2
#define NP 8
#define HD 64
#define NO 16         // NH*NP

// ---------------- K0: weight prep ----------------
// wt2[c][k][o] from attn_w[o][c][k]  (16x128x9 -> 128x9x16)
// pwT[ci][co]  from proj_w[co][ci]   (128x128)
__global__ __launch_bounds__(256) void prep_w_kernel(
    const float* __restrict__ aw, const float* __restrict__ pw,
    float* __restrict__ wt2, float* __restrict__ pwT) {
  int t = blockIdx.x * 256 + threadIdx.x;
  for (int idx = t; idx < 128 * 9 * 16; idx += gridDim.x * 256) {
    int o = idx & 15;
    int rest = idx >> 4;
    int k = rest % 9;
    int c = rest / 9;
    wt2[idx] = aw[o * 1152 + c * 9 + k];
  }
  for (int idx = t; idx < 128 * 128; idx += gridDim.x * 256) {
    int co = idx & 127;
    int ci = idx >> 7;
    pwT[ci * 128 + co] = pw[co * 128 + ci];
  }
}

// ---------------- K1: value transpose to channel-last bf16 ----------------
// value[b][c][h][w] f32 -> val_t[(b*NH+n)*HWH + pix][d] bf16 , c = n*64+d
__global__ __launch_bounds__(256) void transpose_val_kernel(
    const float* __restrict__ value, __hip_bfloat16* __restrict__ val_t) {
  __shared__ float tile[64][65];
  int blk = blockIdx.x;
  int ptile = blk % (HWH / 64);     // 144
  int bn = blk / (HWH / 64);        // 0..15
  int b = bn >> 1, n = bn & 1;
  int pix0 = ptile * 64;
  int t = threadIdx.x;
  int lane = t & 63;
  int row4 = t >> 6;  // 0..3

  const float* src = value + ((size_t)(b * CC + n * 64)) * HWH + pix0;
#pragma unroll
  for (int i = 0; i < 16; ++i) {
    int c = i * 4 + row4;
    tile[c][lane] = src[(size_t)c * HWH + lane];
  }
  __syncthreads();

  __hip_bfloat16* dst = val_t + ((size_t)bn * HWH + pix0) * 64;
  int d2 = t & 31;   // channel pair index
  int ph = t >> 5;   // 0..7
#pragma unroll
  for (int i = 0; i < 8; ++i) {
    int p = i * 8 + ph;
    __hip_bfloat162 v;
    v.x = __float2bfloat16(tile[d2 * 2][p]);
    v.y = __float2bfloat16(tile[d2 * 2 + 1][p]);
    *reinterpret_cast<__hip_bfloat162*>(dst + (size_t)p * 64 + d2 * 2) = v;
  }
}

// ---------------- K2: 3x3 conv (128->16) + per-head softmax ----------------
// attn_out[b*HWH+pix][16], o = n*8+p
__global__ __launch_bounds__(256) void attn_conv_kernel(
    const float* __restrict__ q, const float* __restrict__ wt2,
    const float* __restrict__ bias, float* __restrict__ attn_out) {
  int gid = blockIdx.x * 256 + threadIdx.x;  // 0..73727 (B*HWH)
  int pix = gid % HWH;
  int b = gid / HWH;
  int h = pix / WW, w = pix % WW;

  float acc[16];
#pragma unroll
  for (int o = 0; o < 16; ++o) acc[o] = bias[o];

  const float* qb = q + (size_t)b * CC * HWH;
  bool hm = h > 0, hp = h < HH - 1, wm = w > 0, wp = w < WW - 1;

  for (int c = 0; c < 128; ++c) {
    const float* qc = qb + (size_t)c * HWH + pix;
    float qv[9];
    qv[0] = (hm && wm) ? qc[-WW - 1] : 0.f;
    qv[1] = hm ? qc[-WW] : 0.f;
    qv[2] = (hm && wp) ? qc[-WW + 1] : 0.f;
    qv[3] = wm ? qc[-1] : 0.f;
    qv[4] = qc[0];
    qv[5] = wp ? qc[1] : 0.f;
    qv[6] = (hp && wm) ? qc[WW - 1] : 0.f;
    qv[7] = hp ? qc[WW] : 0.f;
    qv[8] = (hp && wp) ? qc[WW + 1] : 0.f;
    const float* wc = wt2 + c * 144;
#pragma unroll
    for (int k = 0; k < 9; ++k) {
#pragma unroll
      for (int o = 0; o < 16; ++o) acc[o] = fmaf(qv[k], wc[k * 16 + o], acc[o]);
    }
  }

  float out[16];
#pragma unroll
  for (int n = 0; n < 2; ++n) {
    float m = acc[n * 8];
#pragma unroll
    for (int p = 1; p < 8; ++p) m = fmaxf(m, acc[n * 8 + p]);
    float s = 0.f;
#pragma unroll
    for (int p = 0; p < 8; ++p) {
      float e = __expf(acc[n * 8 + p] - m);
      out[n * 8 + p] = e;
      s += e;
    }
    float inv = 1.f / s;
#pragma unroll
    for (int p = 0; p < 8; ++p) out[n * 8 + p] *= inv;
  }

  float4* dst = reinterpret_cast<float4*>(attn_out + (size_t)gid * 16);
#pragma unroll
  for (int i = 0; i < 4; ++i)
    dst[i] = make_float4(out[i * 4], out[i * 4 + 1], out[i * 4 + 2], out[i * 4 + 3]);
}

// ---------------- K3: bilinear sampling + point-weighted sum ----------------
// one wave per (b, n, pix); lane = channel d; writes weighted[b*HWH+pix][n*64+d]
__global__ __launch_bounds__(256) void sample_kernel(
    const __hip_bfloat16* __restrict__ val_t, const float* __restrict__ attn,
    const float* __restrict__ refp, float* __restrict__ weighted) {
  int t = threadIdx.x;
  int lane = t & 63;
  int wid = __builtin_amdgcn_readfirstlane(blockIdx.x * 4 + (t >> 6));
  int bn = wid / HWH;       // 0..15
  int pix = wid % HWH;
  int b = bn >> 1, n = bn & 1;

  const float* ap = attn + (size_t)(b * HWH + pix) * 16 + n * 8;       // 8 uniform floats
  const float* rp = refp + ((size_t)(b * HWH + pix) * NH + n) * 16;    // 16 uniform floats
  const __hip_bfloat16* vb = val_t + (size_t)bn * HWH * 64;

  float acc = 0.f;
#pragma unroll
  for (int p = 0; p < 8; ++p) {
    float a = ap[p];
    float x = rp[p * 2 + 0] * (float)WW - 0.5f;
    float y = rp[p * 2 + 1] * (float)HH - 0.5f;
    float x0f = floorf(x), y0f = floorf(y);
    float wx = x - x0f, wy = y - y0f;
    int x0 = (int)x0f, y0 = (int)y0f;

    float vx0 = (x0 >= 0) ? 1.f : 0.f;
    float vx1 = (x0 < WW - 1) ? 1.f : 0.f;
    float vy0 = (y0 >= 0) ? 1.f : 0.f;
    float vy1 = (y0 < HH - 1) ? 1.f : 0.f;

    int xc0 = max(x0, 0), xc1 = min(x0 + 1, WW - 1);
    int yc0 = max(y0, 0), yc1 = min(y0 + 1, HH - 1);

    float v00 = __bfloat162float(vb[((size_t)yc0 * WW + xc0) * 64 + lane]);
    float v01 = __bfloat162float(vb[((size_t)yc0 * WW + xc1) * 64 + lane]);
    float v10 = __bfloat162float(vb[((size_t)yc1 * WW + xc0) * 64 + lane]);
    float v11 = __bfloat162float(vb[((size_t)yc1 * WW + xc1) * 64 + lane]);

    float w00 = a * (1.f - wy) * (1.f - wx) * vy0 * vx0;
    float w01 = a * (1.f - wy) * wx * vy0 * vx1;
    float w10 = a * wy * (1.f - wx) * vy1 * vx0;
    float w11 = a * wy * wx * vy1 * vx1;

    acc = fmaf(v00, w00, acc);
    acc = fmaf(v01, w01, acc);
    acc = fmaf(v10, w10, acc);
    acc = fmaf(v11, w11, acc);
  }
  weighted[((size_t)b * HWH + pix) * 128 + n * 64 + lane] = acc;
}

// ---------------- K4: 1x1 projection (K=128 GEMM) ----------------
// out[b][co][pix] = pb[co] + sum_ci weighted[b*HWH+pix][ci] * pwT[ci][co]
__global__ __launch_bounds__(256) void proj_kernel(
    const float* __restrict__ weighted, const float* __restrict__ pwT,
    const float* __restrict__ pb, float* __restrict__ out) {
  __shared__ float A[64][129];
  int t = threadIdx.x;
  int pix0 = blockIdx.x * 64;  // global pixel id over B*HWH

  const float* src = weighted + (size_t)pix0 * 128;
#pragma unroll
  for (int i = 0; i < 32; ++i) {
    int idx = i * 256 + t;
    A[idx >> 7][idx & 127] = src[idx];
  }
  __syncthreads();

  int lane = t & 63;                                      // pixel in tile
  int g = __builtin_amdgcn_readfirstlane(t >> 6);         // co group 0..3

  float acc[32];
  const float* pbg = pb + g * 32;
#pragma unroll
  for (int j = 0; j < 32; ++j) acc[j] = pbg[j];

  const float* pwt_g = pwT + g * 32;
  for (int ci = 0; ci < 128; ++ci) {
    float a = A[lane][ci];
    const float* row = pwt_g + (size_t)ci * 128;
#pragma unroll
    for (int j = 0; j < 32; ++j) acc[j] = fmaf(a, row[j], acc[j]);
  }

  int gp = pix0 + lane;
  int b = gp / HWH;
  int pixl = gp % HWH;
  float* ob = out + ((size_t)b * CC + g * 32) * HWH + pixl;
#pragma unroll
  for (int j = 0; j < 32; ++j) ob[(size_t)j * HWH] = acc[j];
}

extern "C" void kernel_launch(void* const* d_in, const int* in_sizes, int n_in,
                              void* d_out, int out_size, void* d_ws, size_t ws_size,
                              hipStream_t stream) {
  const float* query = (const float*)d_in[0];
  const float* value = (const float*)d_in[1];
  const float* refp  = (const float*)d_in[2];
  const float* aw    = (const float*)d_in[3];
  const float* ab    = (const float*)d_in[4];
  const float* pw    = (const float*)d_in[5];
  const float* pb    = (const float*)d_in[6];
  float* out = (float*)d_out;

  char* ws = (char*)d_ws;
  float* wt2            = (float*)(ws);                       //   73728 B
  float* pwT            = (float*)(ws + 73728);               //   65536 B
  float* attn_sm        = (float*)(ws + 139264);              // 4718592 B
  __hip_bfloat16* val_t = (__hip_bfloat16*)(ws + 4857856);    // 18874368 B
  float* weighted       = (float*)(ws + 23732224);            // 37748736 B
  // total 61481K bytes

  prep_w_kernel<<<72, 256, 0, stream>>>(aw, pw, wt2, pwT);
  transpose_val_kernel<<<BB * NH * (HWH / 64), 256, 0, stream>>>(value, val_t);
  attn_conv_kernel<<<(BB * HWH) / 256, 256, 0, stream>>>(query, wt2, ab, attn_sm);
  sample_kernel<<<(BB * NH * HWH) / 4, 256, 0, stream>>>(val_t, attn_sm, refp, weighted);
  proj_kernel<<<(BB * HWH) / 64, 256, 0, stream>>>(weighted, pwT, pb, out);
}